// Round 1
// baseline (1049.419 us; speedup 1.0000x reference)
//
#include <hip/hip_runtime.h>
#include <hip/hip_bf16.h>
#include <cstddef>

#define BB 64
#define TT 400
#define H2 1024
#define EE 256
#define VV 50000
#define KF 2304   // 2*H2 + E
#define KC 1280   // H2 + E

typedef _Float16 half8 __attribute__((ext_vector_type(8)));
typedef float f32x4 __attribute__((ext_vector_type(4)));

// ---------- ws layout (floats) ----------
#define WS_SCORES   0          // 25600
#define WS_ATTN     25600      // 25600
#define WS_CONTEXT  51200      // 65536
#define WS_X        116736     // 16384
#define WS_HNEW     133120     // 65536
#define WS_FEAT     198656     // 147456
#define WS_SRAW     346112     // 25600
#define WS_STATS    371712     // 128

// ---------- d_out layout (floats) ----------
#define OUT_MAIN    0          // 3,200,000
#define OUT_HID     3200000    // 65,536
#define OUT_ATTN    3265536    // 25,600
#define OUT_CPW     3291136    // 25,600

__device__ inline float sigm(float x){ return 1.f/(1.f + __expf(-x)); }

// ============ K1: scores_raw[b,t] = dot(enc[b,t,:], W_align[0:1024]) ============
__global__ void k_scores(const float* __restrict__ enc, const float* __restrict__ Wa,
                         float* __restrict__ scores_raw){
  int wave = threadIdx.x >> 6, lane = threadIdx.x & 63;
  int row = blockIdx.x * 4 + wave;            // < 25600
  const float4* e4 = (const float4*)(enc + (size_t)row * H2);
  const float4* w4 = (const float4*)Wa;
  float acc = 0.f;
#pragma unroll
  for (int i = 0; i < 4; ++i){
    float4 e = e4[i*64 + lane], w = w4[i*64 + lane];
    acc += e.x*w.x + e.y*w.y + e.z*w.z + e.w*w.w;
  }
  for (int m = 32; m >= 1; m >>= 1) acc += __shfl_xor(acc, m, 64);
  if (lane == 0) scores_raw[row] = acc;
}

// ============ K2: per-b: ph_dot, tanh, softmax over T -> attn ============
__global__ void k_attn(const float* __restrict__ scores_raw, const float* __restrict__ pre_hidden,
                       const float* __restrict__ Wa, const float* __restrict__ b_align,
                       float* __restrict__ attn_bt, float* __restrict__ attn_w_out){
  int b = blockIdx.x, t = threadIdx.x;
  __shared__ float red[256];
  const float4* p4 = (const float4*)(pre_hidden + (size_t)b * H2);
  const float4* w4 = (const float4*)(Wa + H2);
  float4 p = p4[t], w = w4[t];
  red[t] = p.x*w.x + p.y*w.y + p.z*w.z + p.w*w.w;
  __syncthreads();
  for (int s = 128; s > 0; s >>= 1){ if (t < s) red[t] += red[t+s]; __syncthreads(); }
  float phd = red[0] + b_align[0];
  __syncthreads();
  int t2 = t + 256;
  float v0 = -1e30f, v1 = -1e30f;
  if (t  < TT) v0 = tanhf(scores_raw[b*TT + t ] + phd);
  if (t2 < TT) v1 = tanhf(scores_raw[b*TT + t2] + phd);
  red[t] = fmaxf(v0, v1); __syncthreads();
  for (int s = 128; s > 0; s >>= 1){ if (t < s) red[t] = fmaxf(red[t], red[t+s]); __syncthreads(); }
  float M = red[0]; __syncthreads();
  float e0 = (t  < TT) ? __expf(v0 - M) : 0.f;
  float e1 = (t2 < TT) ? __expf(v1 - M) : 0.f;
  red[t] = e0 + e1; __syncthreads();
  for (int s = 128; s > 0; s >>= 1){ if (t < s) red[t] += red[t+s]; __syncthreads(); }
  float inv = 1.f / red[0];
  if (t < TT){ float a = e0*inv; attn_bt[b*TT+t] = a; attn_w_out[b*TT+t] = a; }
  if (t2 < TT){ float a = e1*inv; attn_bt[b*TT+t2] = a; attn_w_out[b*TT+t2] = a; }
}

// ============ K3: context[b,h] = sum_t attn[b,t] * enc[b,t,h] ============
__global__ void k_context(const float* __restrict__ enc, const float* __restrict__ attn_bt,
                          float* __restrict__ context){
  int bx = blockIdx.x;
  int b = bx >> 2;
  int h = (bx & 3) * 256 + threadIdx.x;
  const float* e = enc + (size_t)b * TT * H2 + h;
  const float* a = attn_bt + b * TT;
  float acc = 0.f;
  for (int t = 0; t < TT; t += 4){
    acc += a[t  ] * e[(size_t)(t  ) * H2];
    acc += a[t+1] * e[(size_t)(t+1) * H2];
    acc += a[t+2] * e[(size_t)(t+2) * H2];
    acc += a[t+3] * e[(size_t)(t+3) * H2];
  }
  context[b*H2 + h] = acc;
}

// ============ K4a: new_in + feat[emb,context] ============
__global__ void k_newin(const int* __restrict__ input_ids, const float* __restrict__ emb_table,
                        const float* __restrict__ context, const float* __restrict__ W_comb,
                        const float* __restrict__ b_comb, float* __restrict__ x,
                        float* __restrict__ feat){
  int b = blockIdx.x, t = threadIdx.x;
  __shared__ float xs[KC];
  int id = input_ids[b];
  float ev = emb_table[(size_t)id * EE + t];
  xs[t] = ev; feat[b*KF + t] = ev;
#pragma unroll
  for (int q = 0; q < 4; ++q){
    float cv = context[b*H2 + q*256 + t];
    xs[EE + q*256 + t] = cv;
    feat[b*KF + EE + q*256 + t] = cv;
  }
  __syncthreads();
  const float4* w4 = (const float4*)(W_comb + (size_t)t * KC);
  const float4* x4 = (const float4*)xs;
  float acc = b_comb[t];
  for (int k = 0; k < KC/4; ++k){
    float4 w = w4[k], xv = x4[k];
    acc += w.x*xv.x + w.y*xv.y + w.z*xv.z + w.w*xv.w;
  }
  x[b*EE + t] = fmaxf(acc, 0.f);
}

// ============ K4b: GRU -> h_new, current_hidden, feat[h_new] ============
__global__ void k_gru(const float* __restrict__ x, const float* __restrict__ pre_hidden,
                      const float* __restrict__ W_ih, const float* __restrict__ W_hh,
                      const float* __restrict__ b_ih, const float* __restrict__ b_hh,
                      float* __restrict__ h_new, float* __restrict__ feat,
                      float* __restrict__ cur_hid){
  int h = blockIdx.x, t = threadIdx.x;
  __shared__ float wi[768];
  __shared__ float wh[3072];
  wi[t      ] = W_ih[(size_t)(h        ) * EE + t];
  wi[256 + t] = W_ih[(size_t)(H2   + h ) * EE + t];
  wi[512 + t] = W_ih[(size_t)(2*H2 + h ) * EE + t];
#pragma unroll
  for (int q = 0; q < 4; ++q){
    wh[        q*256 + t] = W_hh[(size_t)(h       ) * H2 + q*256 + t];
    wh[1024 +  q*256 + t] = W_hh[(size_t)(H2  + h ) * H2 + q*256 + t];
    wh[2048 +  q*256 + t] = W_hh[(size_t)(2*H2 + h) * H2 + q*256 + t];
  }
  __syncthreads();
  int wave = t >> 6, lane = t & 63;
  float bir = b_ih[h], biz = b_ih[H2+h], bin = b_ih[2*H2+h];
  float bhr = b_hh[h], bhz = b_hh[H2+h], bhn = b_hh[2*H2+h];
  for (int bb = wave*16; bb < wave*16 + 16; ++bb){
    float air=0, aiz=0, ain=0, ahr=0, ahz=0, ahn=0;
#pragma unroll
    for (int i = 0; i < 4; ++i){
      float xv = x[bb*EE + i*64 + lane];
      air += xv * wi[      i*64 + lane];
      aiz += xv * wi[256 + i*64 + lane];
      ain += xv * wi[512 + i*64 + lane];
    }
#pragma unroll
    for (int i = 0; i < 16; ++i){
      float hv = pre_hidden[bb*H2 + i*64 + lane];
      ahr += hv * wh[        i*64 + lane];
      ahz += hv * wh[1024 +  i*64 + lane];
      ahn += hv * wh[2048 +  i*64 + lane];
    }
    for (int m = 32; m >= 1; m >>= 1){
      air += __shfl_xor(air, m, 64); aiz += __shfl_xor(aiz, m, 64); ain += __shfl_xor(ain, m, 64);
      ahr += __shfl_xor(ahr, m, 64); ahz += __shfl_xor(ahz, m, 64); ahn += __shfl_xor(ahn, m, 64);
    }
    if (lane == 0){
      float rg = sigm(air + bir + ahr + bhr);
      float zg = sigm(aiz + biz + ahz + bhz);
      float ng = tanhf(ain + bin + rg*(ahn + bhn));
      float hb = pre_hidden[bb*H2 + h];
      float hn = (1.f - zg)*ng + zg*hb;
      h_new[bb*H2 + h] = hn;
      cur_hid[bb*H2 + h] = hn;
      feat[bb*KF + KC + h] = hn;
    }
  }
}

// ---------- staging helpers: global->regs, regs(cvt fp16)->LDS ----------
__device__ inline void load16(const float* __restrict__ gp, float4* r){
  const float4* g4 = (const float4*)gp;
  r[0] = g4[0]; r[1] = g4[1]; r[2] = g4[2]; r[3] = g4[3];
}
__device__ inline void cvt16(const float4* r, _Float16* lp){
  half8 h0, h1;
  h0[0]=(_Float16)r[0].x; h0[1]=(_Float16)r[0].y; h0[2]=(_Float16)r[0].z; h0[3]=(_Float16)r[0].w;
  h0[4]=(_Float16)r[1].x; h0[5]=(_Float16)r[1].y; h0[6]=(_Float16)r[1].z; h0[7]=(_Float16)r[1].w;
  h1[0]=(_Float16)r[2].x; h1[1]=(_Float16)r[2].y; h1[2]=(_Float16)r[2].z; h1[3]=(_Float16)r[2].w;
  h1[4]=(_Float16)r[3].x; h1[5]=(_Float16)r[3].y; h1[6]=(_Float16)r[3].z; h1[7]=(_Float16)r[3].w;
  *(half8*)(lp)     = h0;
  *(half8*)(lp + 8) = h1;
}

// ============ K5: copy GEMM  G=enc@W_copy^T, fused sigma(G+bc).h_new -> atomic s_raw ======
// M=25600 N=1024 K=1024, BM=BN=128, BK=32, 4 waves (2x2), wave tile 64x64.
// Double-buffered LDS; loads issued 2 K-tiles ahead; 1 barrier per K-step.
__global__ __launch_bounds__(256) void k_gemm_copy(
    const float* __restrict__ A, const float* __restrict__ Wc,
    const float* __restrict__ b_copy, const float* __restrict__ h_new,
    float* __restrict__ s_raw){
  __shared__ _Float16 Ash[2][128*40];
  __shared__ _Float16 Bsh[2][128*40];
  int bx = blockIdx.x;
  int n0 = (bx & 7) * 128;
  int m0 = (bx >> 3) * 128;
  int tid = threadIdx.x;
  int lane = tid & 63, wave = tid >> 6;
  int wm = wave >> 1, wn = wave & 1;
  int quad = lane >> 4, r = lane & 15;
  int srow = tid >> 1, sc0 = (tid & 1) << 4;

  const float* Ap = A  + (size_t)(m0 + srow)*H2 + sc0;
  const float* Bp = Wc + (size_t)(n0 + srow)*H2 + sc0;

  f32x4 acc[4][4];
#pragma unroll
  for (int i = 0; i < 4; ++i)
#pragma unroll
    for (int j = 0; j < 4; ++j) acc[i][j] = (f32x4){0.f,0.f,0.f,0.f};

  float4 ra[4], rb[4];
  // prologue: tile 0 -> LDS[0]; tile 1 -> regs
  load16(Ap, ra); load16(Bp, rb);
  cvt16(ra, &Ash[0][srow*40 + sc0]); cvt16(rb, &Bsh[0][srow*40 + sc0]);
  load16(Ap + 32, ra); load16(Bp + 32, rb);
  __syncthreads();

  const int NT = H2/32;
  for (int kt = 0; kt < NT; ++kt){
    int cur = kt & 1;
    half8 af[4], bf[4];
#pragma unroll
    for (int i = 0; i < 4; ++i) af[i] = *(const half8*)&Ash[cur][(wm*64 + i*16 + r)*40 + quad*8];
#pragma unroll
    for (int j = 0; j < 4; ++j) bf[j] = *(const half8*)&Bsh[cur][(wn*64 + j*16 + r)*40 + quad*8];
    if (kt + 1 < NT){
      cvt16(ra, &Ash[cur^1][srow*40 + sc0]);
      cvt16(rb, &Bsh[cur^1][srow*40 + sc0]);
      if (kt + 2 < NT){
        load16(Ap + (kt+2)*32, ra);
        load16(Bp + (kt+2)*32, rb);
      }
    }
#pragma unroll
    for (int i = 0; i < 4; ++i)
#pragma unroll
      for (int j = 0; j < 4; ++j)
        acc[i][j] = __builtin_amdgcn_mfma_f32_16x16x32_f16(af[i], bf[j], acc[i][j], 0, 0, 0);
    __syncthreads();
  }
  // epilogue: per output row m, partial = sum_n sigmoid(G+bc[n])*h_new[b,n]
#pragma unroll
  for (int i = 0; i < 4; ++i){
#pragma unroll
    for (int rr = 0; rr < 4; ++rr){
      int m_loc = wm*64 + i*16 + quad*4 + rr;
      int m_g = m0 + m_loc;
      int b = m_g / TT;
      float v = 0.f;
#pragma unroll
      for (int j = 0; j < 4; ++j){
        int n_g = n0 + wn*64 + j*16 + r;
        float g = acc[i][j][rr] + b_copy[n_g];
        v += sigm(g) * h_new[b*H2 + n_g];
      }
      v += __shfl_xor(v, 1, 64); v += __shfl_xor(v, 2, 64);
      v += __shfl_xor(v, 4, 64); v += __shfl_xor(v, 8, 64);
      if (r == 0) atomicAdd(&s_raw[m_g], v);
    }
  }
}

// ============ K6: copy softmax over T -> copy_w ============
__global__ void k_copysm(const float* __restrict__ s_raw, float* __restrict__ copy_w){
  int b = blockIdx.x, t = threadIdx.x;
  __shared__ float red[256];
  int t2 = t + 256;
  float v0 = (t  < TT) ? s_raw[b*TT + t ] : -1e30f;
  float v1 = (t2 < TT) ? s_raw[b*TT + t2] : -1e30f;
  red[t] = fmaxf(v0, v1); __syncthreads();
  for (int s = 128; s > 0; s >>= 1){ if (t < s) red[t] = fmaxf(red[t], red[t+s]); __syncthreads(); }
  float M = red[0]; __syncthreads();
  float e0 = (t  < TT) ? __expf(v0 - M) : 0.f;
  float e1 = (t2 < TT) ? __expf(v1 - M) : 0.f;
  red[t] = e0 + e1; __syncthreads();
  for (int s = 128; s > 0; s >>= 1){ if (t < s) red[t] += red[t+s]; __syncthreads(); }
  float inv = 1.f / red[0];
  if (t  < TT) copy_w[b*TT + t ] = e0 * inv;
  if (t2 < TT) copy_w[b*TT + t2] = e1 * inv;
}

// ============ K7: logits = feat @ W_out^T + b_out  (M=50000,N=64,K=2304) ============
// BM=128, BN=64, BK=32, 4 waves (2x2), wave tile 64x32.
// Double-buffered LDS; loads 2 K-tiles ahead; 1 barrier/K-step; Csh aliases staging bufs.
__global__ __launch_bounds__(256) void k_gemm_out(
    const float* __restrict__ Wo, const float* __restrict__ feat,
    const float* __restrict__ b_out, float* __restrict__ logits){
  // Ash: 2*128*40 halves = 20480 B @ 0; Bsh: 2*64*40 halves = 10240 B @ 20480;
  // Csh: 128*65 floats = 33280 B @ 0 (used only after the K-loop's final barrier)
  __shared__ __align__(16) char smem[33280];
  _Float16* AshB = (_Float16*)smem;
  _Float16* BshB = (_Float16*)(smem + 20480);
  float*    Csh  = (float*)smem;

  int m0 = blockIdx.x * 128;
  int tid = threadIdx.x;
  int lane = tid & 63, wave = tid >> 6;
  int wm = wave >> 1, wn = wave & 1;
  int quad = lane >> 4, r = lane & 15;

  f32x4 acc[4][2];
#pragma unroll
  for (int i = 0; i < 4; ++i)
#pragma unroll
    for (int j = 0; j < 2; ++j) acc[i][j] = (f32x4){0.f,0.f,0.f,0.f};

  int arow = tid >> 1, ac0 = (tid & 1) << 4;
  int arow_g = m0 + arow; if (arow_g >= VV) arow_g = VV - 1;   // clamp, results discarded
  const float* Ap = Wo + (size_t)arow_g * KF + ac0;
  const float* Bp = feat + (size_t)arow * KF + ac0;            // valid only for tid<128

  float4 ra[4], rb[4];
  // prologue: tile 0 -> LDS[0]; tile 1 -> regs
  load16(Ap, ra);
  if (tid < 128) load16(Bp, rb);
  cvt16(ra, &AshB[arow*40 + ac0]);
  if (tid < 128) cvt16(rb, &BshB[arow*40 + ac0]);
  load16(Ap + 32, ra);
  if (tid < 128) load16(Bp + 32, rb);
  __syncthreads();

  const int NT = KF/32;   // 72
  for (int kt = 0; kt < NT; ++kt){
    int cur = kt & 1;
    _Float16* Ash = AshB + cur*(128*40);
    _Float16* Bsh = BshB + cur*(64*40);
    half8 af[4], bf[2];
#pragma unroll
    for (int i = 0; i < 4; ++i) af[i] = *(const half8*)&Ash[(wm*64 + i*16 + r)*40 + quad*8];
#pragma unroll
    for (int j = 0; j < 2; ++j) bf[j] = *(const half8*)&Bsh[(wn*32 + j*16 + r)*40 + quad*8];
    if (kt + 1 < NT){
      int nxt = cur ^ 1;
      cvt16(ra, &AshB[nxt*(128*40) + arow*40 + ac0]);
      if (tid < 128) cvt16(rb, &BshB[nxt*(64*40) + arow*40 + ac0]);
      if (kt + 2 < NT){
        load16(Ap + (kt+2)*32, ra);
        if (tid < 128) load16(Bp + (kt+2)*32, rb);
      }
    }
#pragma unroll
    for (int i = 0; i < 4; ++i)
#pragma unroll
      for (int j = 0; j < 2; ++j)
        acc[i][j] = __builtin_amdgcn_mfma_f32_16x16x32_f16(af[i], bf[j], acc[i][j], 0, 0, 0);
    __syncthreads();
  }
  // write tile to LDS with bias, then coalesced transpose-store
  // (safe: K-loop ended with __syncthreads, so all LDS reads of Ash/Bsh are done)
#pragma unroll
  for (int i = 0; i < 4; ++i){
#pragma unroll
    for (int j = 0; j < 2; ++j){
#pragma unroll
      for (int rr = 0; rr < 4; ++rr){
        int m_loc = wm*64 + i*16 + quad*4 + rr;
        int n_loc = wn*32 + j*16 + r;
        int vg = m0 + m_loc;
        float bo = (vg < VV) ? b_out[vg] : 0.f;
        Csh[m_loc*65 + n_loc] = acc[i][j][rr] + bo;
      }
    }
  }
  __syncthreads();
  int vl = tid & 127, grp = tid >> 7;
  int vg = m0 + vl;
  if (vg < VV){
    for (int it = 0; it < 32; ++it){
      int brow = it*2 + grp;
      logits[(size_t)brow * VV + vg] = Csh[vl*65 + brow];
    }
  }
}

// ============ K8: per-b max & inv-sum over V ============
__global__ void k_gensm(const float* __restrict__ logits, float* __restrict__ stats){
  int b = blockIdx.x, t = threadIdx.x;
  __shared__ float red[256];
  const float* row = logits + (size_t)b * VV;
  float m = -1e30f;
  for (int v = t; v < VV; v += 256) m = fmaxf(m, row[v]);
  red[t] = m; __syncthreads();
  for (int s = 128; s > 0; s >>= 1){ if (t < s) red[t] = fmaxf(red[t], red[t+s]); __syncthreads(); }
  float M = red[0]; __syncthreads();
  float sum = 0.f;
  for (int v = t; v < VV; v += 256) sum += __expf(row[v] - M);
  red[t] = sum; __syncthreads();
  for (int s = 128; s > 0; s >>= 1){ if (t < s) red[t] += red[t+s]; __syncthreads(); }
  if (t == 0){ stats[b] = M; stats[64 + b] = 1.f / red[0]; }
}

// ============ K9: out = exp(logit - M)*inv, in place ============
__global__ void k_out(float* __restrict__ out, const float* __restrict__ stats){
  int idx4 = blockIdx.x * 256 + threadIdx.x;   // 800000
  int base = idx4 * 4;
  int b = base / VV;                           // VV divisible by 4
  float M = stats[b], inv = stats[64 + b];
  float4* p = (float4*)(out + base);
  float4 l = *p;
  l.x = __expf(l.x - M) * inv;
  l.y = __expf(l.y - M) * inv;
  l.z = __expf(l.z - M) * inv;
  l.w = __expf(l.w - M) * inv;
  *p = l;
}

// ============ K10: scatter pos: out[b, src[b,t]] += attn[b,t] ============
__global__ void k_scatter(float* __restrict__ out, const int* __restrict__ src,
                          const float* __restrict__ attn_bt){
  int i = blockIdx.x * 256 + threadIdx.x;      // 25600
  int b = i / TT;
  atomicAdd(&out[(size_t)b * VV + src[i]], attn_bt[i]);
}

extern "C" void kernel_launch(void* const* d_in, const int* in_sizes, int n_in,
                              void* d_out, int out_size, void* d_ws, size_t ws_size,
                              hipStream_t stream) {
  const int*   input_ids  = (const int*)  d_in[0];
  const float* pre_hidden = (const float*)d_in[1];
  const float* enc_out    = (const float*)d_in[2];
  const int*   source_in  = (const int*)  d_in[3];
  const float* emb_table  = (const float*)d_in[4];
  const float* W_align    = (const float*)d_in[5];
  const float* b_align    = (const float*)d_in[6];
  const float* W_ih       = (const float*)d_in[7];
  const float* W_hh       = (const float*)d_in[8];
  const float* b_ih       = (const float*)d_in[9];
  const float* b_hh       = (const float*)d_in[10];
  const float* W_comb     = (const float*)d_in[11];
  const float* b_comb     = (const float*)d_in[12];
  const float* W_out      = (const float*)d_in[13];
  const float* b_out      = (const float*)d_in[14];
  const float* W_copy     = (const float*)d_in[15];
  const float* b_copy     = (const float*)d_in[16];

  float* ws = (float*)d_ws;
  float* scores_raw = ws + WS_SCORES;
  float* attn_bt    = ws + WS_ATTN;
  float* context    = ws + WS_CONTEXT;
  float* x          = ws + WS_X;
  float* h_new      = ws + WS_HNEW;
  float* feat       = ws + WS_FEAT;
  float* s_raw      = ws + WS_SRAW;
  float* stats      = ws + WS_STATS;

  float* out        = (float*)d_out;
  float* out_hid    = out + OUT_HID;
  float* out_attn   = out + OUT_ATTN;
  float* out_cpw    = out + OUT_CPW;

  hipMemsetAsync(s_raw, 0, BB*TT*sizeof(float), stream);

  k_scores <<<BB*TT/4, 256, 0, stream>>>(enc_out, W_align, scores_raw);
  k_attn   <<<BB,      256, 0, stream>>>(scores_raw, pre_hidden, W_align, b_align, attn_bt, out_attn);
  k_context<<<BB*4,    256, 0, stream>>>(enc_out, attn_bt, context);
  k_newin  <<<BB,      256, 0, stream>>>(input_ids, emb_table, context, W_comb, b_comb, x, feat);
  k_gru    <<<H2,      256, 0, stream>>>(x, pre_hidden, W_ih, W_hh, b_ih, b_hh, h_new, feat, out_hid);
  k_gemm_copy<<<(BB*TT/128)*(H2/128), 256, 0, stream>>>(enc_out, W_copy, b_copy, h_new, s_raw);
  k_copysm <<<BB,      256, 0, stream>>>(s_raw, out_cpw);
  k_gemm_out<<<(VV + 127)/128, 256, 0, stream>>>(W_out, feat, b_out, out);
  k_gensm  <<<BB,      256, 0, stream>>>(out, stats);
  k_out    <<<BB*VV/1024, 256, 0, stream>>>(out, stats);
  k_scatter<<<BB*TT/256, 256, 0, stream>>>(out, source_in, attn_bt);
}

// Round 3
// 968.328 us; speedup vs baseline: 1.0837x; 1.0837x over previous
//
#include <hip/hip_runtime.h>
#include <hip/hip_bf16.h>
#include <cstddef>

#define BB 64
#define TT 400
#define H2 1024
#define EE 256
#define VV 50000
#define KF 2304   // 2*H2 + E
#define KC 1280   // H2 + E

typedef _Float16 half8 __attribute__((ext_vector_type(8)));
typedef _Float16 half4 __attribute__((ext_vector_type(4)));
typedef float f32x4 __attribute__((ext_vector_type(4)));

// ---------- ws layout (floats) ----------
#define WS_SCORES   0          // 25600
#define WS_ATTN     25600      // 25600
#define WS_CONTEXT  51200      // 65536
#define WS_X        116736     // 16384
#define WS_HNEW     133120     // 65536
#define WS_FEAT     198656     // 147456
#define WS_SRAW     346112     // 25600
#define WS_STATS    371712     // 512
#define WS_ENCH     372224     // 13,107,200 floats (26.2M halves)
#define WS_WCH      13479424   // 262,144 floats (1M halves)

// ---------- d_out layout (floats) ----------
#define OUT_MAIN    0          // 3,200,000
#define OUT_HID     3200000    // 65,536
#define OUT_ATTN    3265536    // 25,600
#define OUT_CPW     3291136    // 25,600

__device__ inline float sigm(float x){ return 1.f/(1.f + __expf(-x)); }

// ============ K0: fp32 -> fp16 bulk convert (8 floats/thread) ============
__global__ void k_cvt16(const float* __restrict__ src, _Float16* __restrict__ dst){
  int i = blockIdx.x * 256 + threadIdx.x;
  const float4* s4 = (const float4*)src;
  float4 a = s4[i*2], b = s4[i*2+1];
  half8 h;
  h[0]=(_Float16)a.x; h[1]=(_Float16)a.y; h[2]=(_Float16)a.z; h[3]=(_Float16)a.w;
  h[4]=(_Float16)b.x; h[5]=(_Float16)b.y; h[6]=(_Float16)b.z; h[7]=(_Float16)b.w;
  *(half8*)(dst + (size_t)i*8) = h;
}

// ============ K1: scores_raw[b,t] = dot(enc[b,t,:], W_align[0:1024]); side-write enc fp16 ============
__global__ void k_scores(const float* __restrict__ enc, const float* __restrict__ Wa,
                         float* __restrict__ scores_raw, _Float16* __restrict__ encH){
  int wave = threadIdx.x >> 6, lane = threadIdx.x & 63;
  int row = blockIdx.x * 4 + wave;            // < 25600
  const float4* e4 = (const float4*)(enc + (size_t)row * H2);
  const float4* w4 = (const float4*)Wa;
  _Float16* eh = encH + (size_t)row * H2;
  float acc = 0.f;
#pragma unroll
  for (int i = 0; i < 4; ++i){
    float4 e = e4[i*64 + lane], w = w4[i*64 + lane];
    acc += e.x*w.x + e.y*w.y + e.z*w.z + e.w*w.w;
    half4 h; h[0]=(_Float16)e.x; h[1]=(_Float16)e.y; h[2]=(_Float16)e.z; h[3]=(_Float16)e.w;
    *(half4*)(eh + (size_t)(i*64 + lane)*4) = h;
  }
  for (int m = 32; m >= 1; m >>= 1) acc += __shfl_xor(acc, m, 64);
  if (lane == 0) scores_raw[row] = acc;
}

// ============ K2: per-b: ph_dot, tanh, softmax over T -> attn ============
__global__ void k_attn(const float* __restrict__ scores_raw, const float* __restrict__ pre_hidden,
                       const float* __restrict__ Wa, const float* __restrict__ b_align,
                       float* __restrict__ attn_bt, float* __restrict__ attn_w_out){
  int b = blockIdx.x, t = threadIdx.x;
  __shared__ float red[256];
  const float4* p4 = (const float4*)(pre_hidden + (size_t)b * H2);
  const float4* w4 = (const float4*)(Wa + H2);
  float4 p = p4[t], w = w4[t];
  red[t] = p.x*w.x + p.y*w.y + p.z*w.z + p.w*w.w;
  __syncthreads();
  for (int s = 128; s > 0; s >>= 1){ if (t < s) red[t] += red[t+s]; __syncthreads(); }
  float phd = red[0] + b_align[0];
  __syncthreads();
  int t2 = t + 256;
  float v0 = -1e30f, v1 = -1e30f;
  if (t  < TT) v0 = tanhf(scores_raw[b*TT + t ] + phd);
  if (t2 < TT) v1 = tanhf(scores_raw[b*TT + t2] + phd);
  red[t] = fmaxf(v0, v1); __syncthreads();
  for (int s = 128; s > 0; s >>= 1){ if (t < s) red[t] = fmaxf(red[t], red[t+s]); __syncthreads(); }
  float M = red[0]; __syncthreads();
  float e0 = (t  < TT) ? __expf(v0 - M) : 0.f;
  float e1 = (t2 < TT) ? __expf(v1 - M) : 0.f;
  red[t] = e0 + e1; __syncthreads();
  for (int s = 128; s > 0; s >>= 1){ if (t < s) red[t] += red[t+s]; __syncthreads(); }
  float inv = 1.f / red[0];
  if (t < TT){ float a = e0*inv; attn_bt[b*TT+t] = a; attn_w_out[b*TT+t] = a; }
  if (t2 < TT){ float a = e1*inv; attn_bt[b*TT+t2] = a; attn_w_out[b*TT+t2] = a; }
}

// ============ K3: context[b,h] = sum_t attn[b,t] * enc[b,t,h] ============
__global__ void k_context(const float* __restrict__ enc, const float* __restrict__ attn_bt,
                          float* __restrict__ context){
  int bx = blockIdx.x;
  int b = bx >> 2;
  int h = (bx & 3) * 256 + threadIdx.x;
  const float* e = enc + (size_t)b * TT * H2 + h;
  const float* a = attn_bt + b * TT;
  float acc = 0.f;
  for (int t = 0; t < TT; t += 4){
    acc += a[t  ] * e[(size_t)(t  ) * H2];
    acc += a[t+1] * e[(size_t)(t+1) * H2];
    acc += a[t+2] * e[(size_t)(t+2) * H2];
    acc += a[t+3] * e[(size_t)(t+3) * H2];
  }
  context[b*H2 + h] = acc;
}

// ============ K4a: new_in + feat[emb,context] ============
__global__ void k_newin(const int* __restrict__ input_ids, const float* __restrict__ emb_table,
                        const float* __restrict__ context, const float* __restrict__ W_comb,
                        const float* __restrict__ b_comb, float* __restrict__ x,
                        float* __restrict__ feat){
  int b = blockIdx.x, t = threadIdx.x;
  __shared__ float xs[KC];
  int id = input_ids[b];
  float ev = emb_table[(size_t)id * EE + t];
  xs[t] = ev; feat[b*KF + t] = ev;
#pragma unroll
  for (int q = 0; q < 4; ++q){
    float cv = context[b*H2 + q*256 + t];
    xs[EE + q*256 + t] = cv;
    feat[b*KF + EE + q*256 + t] = cv;
  }
  __syncthreads();
  const float4* w4 = (const float4*)(W_comb + (size_t)t * KC);
  const float4* x4 = (const float4*)xs;
  float acc = b_comb[t];
  for (int k = 0; k < KC/4; ++k){
    float4 w = w4[k], xv = x4[k];
    acc += w.x*xv.x + w.y*xv.y + w.z*xv.z + w.w*xv.w;
  }
  x[b*EE + t] = fmaxf(acc, 0.f);
}

// ============ K4b: GRU -> h_new, current_hidden, feat[h_new] ============
__global__ void k_gru(const float* __restrict__ x, const float* __restrict__ pre_hidden,
                      const float* __restrict__ W_ih, const float* __restrict__ W_hh,
                      const float* __restrict__ b_ih, const float* __restrict__ b_hh,
                      float* __restrict__ h_new, float* __restrict__ feat,
                      float* __restrict__ cur_hid){
  int h = blockIdx.x, t = threadIdx.x;
  __shared__ float wi[768];
  __shared__ float wh[3072];
  wi[t      ] = W_ih[(size_t)(h        ) * EE + t];
  wi[256 + t] = W_ih[(size_t)(H2   + h ) * EE + t];
  wi[512 + t] = W_ih[(size_t)(2*H2 + h ) * EE + t];
#pragma unroll
  for (int q = 0; q < 4; ++q){
    wh[        q*256 + t] = W_hh[(size_t)(h       ) * H2 + q*256 + t];
    wh[1024 +  q*256 + t] = W_hh[(size_t)(H2  + h ) * H2 + q*256 + t];
    wh[2048 +  q*256 + t] = W_hh[(size_t)(2*H2 + h) * H2 + q*256 + t];
  }
  __syncthreads();
  int wave = t >> 6, lane = t & 63;
  float bir = b_ih[h], biz = b_ih[H2+h], bin = b_ih[2*H2+h];
  float bhr = b_hh[h], bhz = b_hh[H2+h], bhn = b_hh[2*H2+h];
  for (int bb = wave*16; bb < wave*16 + 16; ++bb){
    float air=0, aiz=0, ain=0, ahr=0, ahz=0, ahn=0;
#pragma unroll
    for (int i = 0; i < 4; ++i){
      float xv = x[bb*EE + i*64 + lane];
      air += xv * wi[      i*64 + lane];
      aiz += xv * wi[256 + i*64 + lane];
      ain += xv * wi[512 + i*64 + lane];
    }
#pragma unroll
    for (int i = 0; i < 16; ++i){
      float hv = pre_hidden[bb*H2 + i*64 + lane];
      ahr += hv * wh[        i*64 + lane];
      ahz += hv * wh[1024 +  i*64 + lane];
      ahn += hv * wh[2048 +  i*64 + lane];
    }
    for (int m = 32; m >= 1; m >>= 1){
      air += __shfl_xor(air, m, 64); aiz += __shfl_xor(aiz, m, 64); ain += __shfl_xor(ain, m, 64);
      ahr += __shfl_xor(ahr, m, 64); ahz += __shfl_xor(ahz, m, 64); ahn += __shfl_xor(ahn, m, 64);
    }
    if (lane == 0){
      float rg = sigm(air + bir + ahr + bhr);
      float zg = sigm(aiz + biz + ahz + bhz);
      float ng = tanhf(ain + bin + rg*(ahn + bhn));
      float hb = pre_hidden[bb*H2 + h];
      float hn = (1.f - zg)*ng + zg*hb;
      h_new[bb*H2 + h] = hn;
      cur_hid[bb*H2 + h] = hn;
      feat[bb*KF + KC + h] = hn;
    }
  }
}

// ---------- staging helpers ----------
__device__ inline void load8(const float* __restrict__ gp, float4* r){
  const float4* g4 = (const float4*)gp;
  r[0] = g4[0]; r[1] = g4[1];
}
__device__ inline void cvt8(const float4* r, _Float16* lp){
  half8 h;
  h[0]=(_Float16)r[0].x; h[1]=(_Float16)r[0].y; h[2]=(_Float16)r[0].z; h[3]=(_Float16)r[0].w;
  h[4]=(_Float16)r[1].x; h[5]=(_Float16)r[1].y; h[6]=(_Float16)r[1].z; h[7]=(_Float16)r[1].w;
  *(half8*)lp = h;
}

// ============ K5: copy GEMM  G=encH@WcH^T (fp16 in global), fused sigma(G+bc).h_new -> atomic s_raw
// M=25600 N=1024 K=1024, BM=BN=128, BK=32, 4 waves (2x2), wave tile 64x64.
// fp16 A/B loads: no cvt in the K-loop. Double-buffered LDS, depth-2 reg prefetch, 1 barrier/step.
__global__ __launch_bounds__(256) void k_gemm_copy(
    const _Float16* __restrict__ A, const _Float16* __restrict__ Wc,
    const float* __restrict__ b_copy, const float* __restrict__ h_new,
    float* __restrict__ s_raw){
  __shared__ _Float16 Ash[2][128*40];
  __shared__ _Float16 Bsh[2][128*40];
  int bx = blockIdx.x;
  int n0 = (bx & 7) * 128;
  int m0 = (bx >> 3) * 128;
  int tid = threadIdx.x;
  int lane = tid & 63, wave = tid >> 6;
  int wm = wave >> 1, wn = wave & 1;
  int quad = lane >> 4, r = lane & 15;
  int srow = tid >> 1, sc0 = (tid & 1) << 4;   // 16 halves per thread

  const _Float16* Ap = A  + (size_t)(m0 + srow)*H2 + sc0;
  const _Float16* Bp = Wc + (size_t)(n0 + srow)*H2 + sc0;

  f32x4 acc[4][4];
#pragma unroll
  for (int i = 0; i < 4; ++i)
#pragma unroll
    for (int j = 0; j < 4; ++j) acc[i][j] = (f32x4){0.f,0.f,0.f,0.f};

  // prologue: tile 0 -> LDS[0] direct; tile 1 -> regs
  {
    half8 a0 = *(const half8*)(Ap), a1 = *(const half8*)(Ap+8);
    half8 b0 = *(const half8*)(Bp), b1 = *(const half8*)(Bp+8);
    *(half8*)&Ash[0][srow*40 + sc0] = a0; *(half8*)&Ash[0][srow*40 + sc0 + 8] = a1;
    *(half8*)&Bsh[0][srow*40 + sc0] = b0; *(half8*)&Bsh[0][srow*40 + sc0 + 8] = b1;
  }
  half8 raL = *(const half8*)(Ap+32), raH = *(const half8*)(Ap+40);
  half8 rbL = *(const half8*)(Bp+32), rbH = *(const half8*)(Bp+40);
  __syncthreads();

  const int NT = H2/32;
  for (int kt = 0; kt < NT; ++kt){
    int cur = kt & 1;
    half8 af[4], bf[4];
#pragma unroll
    for (int i = 0; i < 4; ++i) af[i] = *(const half8*)&Ash[cur][(wm*64 + i*16 + r)*40 + quad*8];
#pragma unroll
    for (int j = 0; j < 4; ++j) bf[j] = *(const half8*)&Bsh[cur][(wn*64 + j*16 + r)*40 + quad*8];
    if (kt + 1 < NT){
      *(half8*)&Ash[cur^1][srow*40 + sc0]     = raL;
      *(half8*)&Ash[cur^1][srow*40 + sc0 + 8] = raH;
      *(half8*)&Bsh[cur^1][srow*40 + sc0]     = rbL;
      *(half8*)&Bsh[cur^1][srow*40 + sc0 + 8] = rbH;
      if (kt + 2 < NT){
        raL = *(const half8*)(Ap + (kt+2)*32); raH = *(const half8*)(Ap + (kt+2)*32 + 8);
        rbL = *(const half8*)(Bp + (kt+2)*32); rbH = *(const half8*)(Bp + (kt+2)*32 + 8);
      }
    }
#pragma unroll
    for (int i = 0; i < 4; ++i)
#pragma unroll
      for (int j = 0; j < 4; ++j)
        acc[i][j] = __builtin_amdgcn_mfma_f32_16x16x32_f16(af[i], bf[j], acc[i][j], 0, 0, 0);
    __syncthreads();
  }
  // epilogue: per output row m, partial = sum_n sigmoid(G+bc[n])*h_new[b,n]
#pragma unroll
  for (int i = 0; i < 4; ++i){
#pragma unroll
    for (int rr = 0; rr < 4; ++rr){
      int m_loc = wm*64 + i*16 + quad*4 + rr;
      int m_g = m0 + m_loc;
      int b = m_g / TT;
      float v = 0.f;
#pragma unroll
      for (int j = 0; j < 4; ++j){
        int n_g = n0 + wn*64 + j*16 + r;
        float g = acc[i][j][rr] + b_copy[n_g];
        v += sigm(g) * h_new[b*H2 + n_g];
      }
      v += __shfl_xor(v, 1, 64); v += __shfl_xor(v, 2, 64);
      v += __shfl_xor(v, 4, 64); v += __shfl_xor(v, 8, 64);
      if (r == 0) atomicAdd(&s_raw[m_g], v);
    }
  }
}

// ============ K6: copy softmax over T -> copy_w ============
__global__ void k_copysm(const float* __restrict__ s_raw, float* __restrict__ copy_w){
  int b = blockIdx.x, t = threadIdx.x;
  __shared__ float red[256];
  int t2 = t + 256;
  float v0 = (t  < TT) ? s_raw[b*TT + t ] : -1e30f;
  float v1 = (t2 < TT) ? s_raw[b*TT + t2] : -1e30f;
  red[t] = fmaxf(v0, v1); __syncthreads();
  for (int s = 128; s > 0; s >>= 1){ if (t < s) red[t] = fmaxf(red[t], red[t+s]); __syncthreads(); }
  float M = red[0]; __syncthreads();
  float e0 = (t  < TT) ? __expf(v0 - M) : 0.f;
  float e1 = (t2 < TT) ? __expf(v1 - M) : 0.f;
  red[t] = e0 + e1; __syncthreads();
  for (int s = 128; s > 0; s >>= 1){ if (t < s) red[t] += red[t+s]; __syncthreads(); }
  float inv = 1.f / red[0];
  if (t  < TT) copy_w[b*TT + t ] = e0 * inv;
  if (t2 < TT) copy_w[b*TT + t2] = e1 * inv;
}

// ============ K7: logits = feat @ W_out^T + b_out  (M=50000,N=64,K=2304) ============
// BM=64, BN=64 (full N), BK=32, 4 waves (2x2), wave tile 32x32. 782 blocks (~3/CU).
// Depth-3 reg prefetch (2 reg sets, static 2-unroll), 1 barrier/step, Csh aliases staging.
__global__ __launch_bounds__(256) void k_gemm_out(
    const float* __restrict__ Wo, const float* __restrict__ feat,
    const float* __restrict__ b_out, float* __restrict__ logits){
  // Ash: 2*64*40 halves = 10240 B @0; Bsh: same @10240; Csh: 64*65 floats = 16640 B aliased @0
  __shared__ __align__(16) char smem[20480];
  _Float16* AshB = (_Float16*)smem;            // [2][64*40]
  _Float16* BshB = (_Float16*)(smem + 10240);  // [2][64*40]
  float*    Csh  = (float*)smem;

  int m0 = blockIdx.x * 64;
  int tid = threadIdx.x;
  int lane = tid & 63, wave = tid >> 6;
  int wm = wave >> 1, wn = wave & 1;
  int quad = lane >> 4, r = lane & 15;

  f32x4 acc[2][2];
#pragma unroll
  for (int i = 0; i < 2; ++i)
#pragma unroll
    for (int j = 0; j < 2; ++j) acc[i][j] = (f32x4){0.f,0.f,0.f,0.f};

  int arow = tid >> 2, ac0 = (tid & 3) << 3;   // 8 floats per thread
  int arow_g = m0 + arow; if (arow_g >= VV) arow_g = VV - 1;   // clamp, results discarded
  const float* Ap = Wo  + (size_t)arow_g * KF + ac0;
  const float* Bp = feat + (size_t)arow  * KF + ac0;           // arow < 64 = full batch

  float4 a0[2], b0[2], aA[2], bA[2], aB[2], bB[2];
  // prologue: tile0 -> LDS[0]; tile1 -> setA; tile2 -> setB
  load8(Ap, a0); load8(Bp, b0);
  cvt8(a0, &AshB[arow*40 + ac0]);
  cvt8(b0, &BshB[arow*40 + ac0]);
  load8(Ap + 32, aA); load8(Bp + 32, bA);
  load8(Ap + 64, aB); load8(Bp + 64, bB);
  __syncthreads();

  const int NT = KF/32;   // 72 (even)
  for (int kt = 0; kt < NT; kt += 2){
    { // even phase: compute LDS[0], stage kt+1 -> LDS[1] from setA, load kt+3 -> setA
      half8 af[2], bf[2];
#pragma unroll
      for (int i = 0; i < 2; ++i) af[i] = *(const half8*)&AshB[(wm*32 + i*16 + r)*40 + quad*8];
#pragma unroll
      for (int j = 0; j < 2; ++j) bf[j] = *(const half8*)&BshB[(wn*32 + j*16 + r)*40 + quad*8];
      if (kt + 1 < NT){
        cvt8(aA, &AshB[2560 + arow*40 + ac0]);
        cvt8(bA, &BshB[2560 + arow*40 + ac0]);
        if (kt + 3 < NT){ load8(Ap + (kt+3)*32, aA); load8(Bp + (kt+3)*32, bA); }
      }
#pragma unroll
      for (int i = 0; i < 2; ++i)
#pragma unroll
        for (int j = 0; j < 2; ++j)
          acc[i][j] = __builtin_amdgcn_mfma_f32_16x16x32_f16(af[i], bf[j], acc[i][j], 0, 0, 0);
      __syncthreads();
    }
    if (kt + 1 < NT){ // odd phase: compute LDS[1], stage kt+2 -> LDS[0] from setB, load kt+4 -> setB
      half8 af[2], bf[2];
#pragma unroll
      for (int i = 0; i < 2; ++i) af[i] = *(const half8*)&AshB[2560 + (wm*32 + i*16 + r)*40 + quad*8];
#pragma unroll
      for (int j = 0; j < 2; ++j) bf[j] = *(const half8*)&BshB[2560 + (wn*32 + j*16 + r)*40 + quad*8];
      if (kt + 2 < NT){
        cvt8(aB, &AshB[arow*40 + ac0]);
        cvt8(bB, &BshB[arow*40 + ac0]);
        if (kt + 4 < NT){ load8(Ap + (kt+4)*32, aB); load8(Bp + (kt+4)*32, bB); }
      }
#pragma unroll
      for (int i = 0; i < 2; ++i)
#pragma unroll
        for (int j = 0; j < 2; ++j)
          acc[i][j] = __builtin_amdgcn_mfma_f32_16x16x32_f16(af[i], bf[j], acc[i][j], 0, 0, 0);
      __syncthreads();
    }
  }
  // write tile to LDS with bias, then coalesced transpose-store (after final barrier above)
#pragma unroll
  for (int i = 0; i < 2; ++i){
#pragma unroll
    for (int j = 0; j < 2; ++j){
#pragma unroll
      for (int rr = 0; rr < 4; ++rr){
        int m_loc = wm*32 + i*16 + quad*4 + rr;
        int n_loc = wn*32 + j*16 + r;
        int vg = m0 + m_loc;
        float bo = (vg < VV) ? b_out[vg] : 0.f;
        Csh[m_loc*65 + n_loc] = acc[i][j][rr] + bo;
      }
    }
  }
  __syncthreads();
  int vl = tid & 63, grp = tid >> 6;
  int vg = m0 + vl;
  if (vg < VV){
    for (int it = 0; it < 16; ++it){
      int brow = it*4 + grp;
      logits[(size_t)brow * VV + vg] = Csh[vl*65 + brow];
    }
  }
}

// ============ K8: per-(b,quarter) max & sum over V/4 ============
__global__ void k_gensm(const float* __restrict__ logits, float* __restrict__ stats){
  int bq = blockIdx.x;             // 256 = 64 b x 4 quarters
  int b = bq >> 2, q = bq & 3;
  int t = threadIdx.x;
  __shared__ float red[256];
  const float* row = logits + (size_t)b * VV + q * 12500;
  float m = -1e30f;
  for (int v = t; v < 12500; v += 256) m = fmaxf(m, row[v]);
  red[t] = m; __syncthreads();
  for (int s = 128; s > 0; s >>= 1){ if (t < s) red[t] = fmaxf(red[t], red[t+s]); __syncthreads(); }
  float M = red[0]; __syncthreads();
  float sum = 0.f;
  for (int v = t; v < 12500; v += 256) sum += __expf(row[v] - M);
  red[t] = sum; __syncthreads();
  for (int s = 128; s > 0; s >>= 1){ if (t < s) red[t] += red[t+s]; __syncthreads(); }
  if (t == 0){ stats[bq] = M; stats[256 + bq] = red[0]; }
}

// ============ K9: out = exp(logit - M)*inv, in place (combines quarter-stats) ============
__global__ void k_out(float* __restrict__ out, const float* __restrict__ stats){
  int idx4 = blockIdx.x * 256 + threadIdx.x;   // 800000
  int base = idx4 * 4;
  int b = base / VV;                           // VV divisible by 4
  float m0 = stats[4*b], m1 = stats[4*b+1], m2 = stats[4*b+2], m3 = stats[4*b+3];
  float M = fmaxf(fmaxf(m0, m1), fmaxf(m2, m3));
  float s = stats[256 + 4*b  ] * __expf(m0 - M)
          + stats[256 + 4*b+1] * __expf(m1 - M)
          + stats[256 + 4*b+2] * __expf(m2 - M)
          + stats[256 + 4*b+3] * __expf(m3 - M);
  float inv = 1.f / s;
  float4* p = (float4*)(out + base);
  float4 l = *p;
  l.x = __expf(l.x - M) * inv;
  l.y = __expf(l.y - M) * inv;
  l.z = __expf(l.z - M) * inv;
  l.w = __expf(l.w - M) * inv;
  *p = l;
}

// ============ K10: scatter pos: out[b, src[b,t]] += attn[b,t] ============
__global__ void k_scatter(float* __restrict__ out, const int* __restrict__ src,
                          const float* __restrict__ attn_bt){
  int i = blockIdx.x * 256 + threadIdx.x;      // 25600
  int b = i / TT;
  atomicAdd(&out[(size_t)b * VV + src[i]], attn_bt[i]);
}

extern "C" void kernel_launch(void* const* d_in, const int* in_sizes, int n_in,
                              void* d_out, int out_size, void* d_ws, size_t ws_size,
                              hipStream_t stream) {
  const int*   input_ids  = (const int*)  d_in[0];
  const float* pre_hidden = (const float*)d_in[1];
  const float* enc_out    = (const float*)d_in[2];
  const int*   source_in  = (const int*)  d_in[3];
  const float* emb_table  = (const float*)d_in[4];
  const float* W_align    = (const float*)d_in[5];
  const float* b_align    = (const float*)d_in[6];
  const float* W_ih       = (const float*)d_in[7];
  const float* W_hh       = (const float*)d_in[8];
  const float* b_ih       = (const float*)d_in[9];
  const float* b_hh       = (const float*)d_in[10];
  const float* W_comb     = (const float*)d_in[11];
  const float* b_comb     = (const float*)d_in[12];
  const float* W_out      = (const float*)d_in[13];
  const float* b_out      = (const float*)d_in[14];
  const float* W_copy     = (const float*)d_in[15];
  const float* b_copy     = (const float*)d_in[16];

  float* ws = (float*)d_ws;
  float* scores_raw = ws + WS_SCORES;
  float* attn_bt    = ws + WS_ATTN;
  float* context    = ws + WS_CONTEXT;
  float* x          = ws + WS_X;
  float* h_new      = ws + WS_HNEW;
  float* feat       = ws + WS_FEAT;
  float* s_raw      = ws + WS_SRAW;
  float* stats      = ws + WS_STATS;
  _Float16* enc_h   = (_Float16*)(ws + WS_ENCH);
  _Float16* wc_h    = (_Float16*)(ws + WS_WCH);

  float* out        = (float*)d_out;
  float* out_hid    = out + OUT_HID;
  float* out_attn   = out + OUT_ATTN;
  float* out_cpw    = out + OUT_CPW;

  hipMemsetAsync(s_raw, 0, BB*TT*sizeof(float), stream);

  k_cvt16  <<<H2*H2/8/256, 256, 0, stream>>>(W_copy, wc_h);     // 512 blocks
  k_scores <<<BB*TT/4, 256, 0, stream>>>(enc_out, W_align, scores_raw, enc_h);
  k_attn   <<<BB,      256, 0, stream>>>(scores_raw, pre_hidden, W_align, b_align, attn_bt, out_attn);
  k_context<<<BB*4,    256, 0, stream>>>(enc_out, attn_bt, context);
  k_newin  <<<BB,      256, 0, stream>>>(input_ids, emb_table, context, W_comb, b_comb, x, feat);
  k_gru    <<<H2,      256, 0, stream>>>(x, pre_hidden, W_ih, W_hh, b_ih, b_hh, h_new, feat, out_hid);
  k_gemm_copy<<<(BB*TT/128)*(H2/128), 256, 0, stream>>>(enc_h, wc_h, b_copy, h_new, s_raw);
  k_copysm <<<BB,      256, 0, stream>>>(s_raw, out_cpw);
  k_gemm_out<<<(VV + 63)/64, 256, 0, stream>>>(W_out, feat, b_out, out);
  k_gensm  <<<BB*4,    256, 0, stream>>>(out, stats);
  k_out    <<<BB*VV/1024, 256, 0, stream>>>(out, stats);
  k_scatter<<<BB*TT/256, 256, 0, stream>>>(out, source_in, attn_bt);
}